// Round 1
// baseline (327.387 us; speedup 1.0000x reference)
//
#include <hip/hip_runtime.h>

#define HIDDEN 128

// Wsym[i][j] = W[i][j] + W[j][i]
__global__ __launch_bounds__(256) void symmetrize_w(const float* __restrict__ w,
                                                    float* __restrict__ wsym) {
    int idx = blockIdx.x * 256 + threadIdx.x;   // 0..16383
    int i = idx >> 7, j = idx & 127;
    wsym[idx] = w[idx] + w[j * HIDDEN + i];
}

// U = z @ Wsym : [N,128] x [128,128] -> [N,128]
// Block = 256 thr (4 waves). Wsym fully staged in LDS (64 KB -> 2 blocks/CU).
// Each wave owns 8 rows; each lane owns cols {lane, lane+64}.
// z read as wave-uniform float4 broadcast loads (each element read once/block).
__global__ __launch_bounds__(256) void gemm_u(const float* __restrict__ z,
                                              const float* __restrict__ wsym,
                                              float* __restrict__ u, int nrows) {
    __shared__ float wl[HIDDEN * HIDDEN];   // 64 KB
    int tid = threadIdx.x;
    const float4* w4 = (const float4*)wsym;
    float4* wl4 = (float4*)wl;
    #pragma unroll
    for (int i = 0; i < 16; ++i) wl4[tid + 256 * i] = w4[tid + 256 * i];
    __syncthreads();

    int wave = tid >> 6, lane = tid & 63;
    int row0 = blockIdx.x * 32 + wave * 8;
    if (row0 + 8 > nrows) return;   // N=100000 is a multiple of 32; never taken

    const float* zb = z + (size_t)row0 * HIDDEN;
    float acc0[8], acc1[8];
    #pragma unroll
    for (int r = 0; r < 8; ++r) { acc0[r] = 0.f; acc1[r] = 0.f; }

    #pragma unroll 2
    for (int k0 = 0; k0 < HIDDEN; k0 += 4) {
        float4 zv[8];
        #pragma unroll
        for (int r = 0; r < 8; ++r)
            zv[r] = *(const float4*)(zb + r * HIDDEN + k0);   // wave-uniform broadcast
        float wa[4], wb[4];
        #pragma unroll
        for (int i = 0; i < 4; ++i) {
            wa[i] = wl[(k0 + i) * HIDDEN + lane];        // 2-way LDS alias: free
            wb[i] = wl[(k0 + i) * HIDDEN + lane + 64];
        }
        #pragma unroll
        for (int r = 0; r < 8; ++r) {
            acc0[r] = fmaf(zv[r].x, wa[0], acc0[r]);
            acc0[r] = fmaf(zv[r].y, wa[1], acc0[r]);
            acc0[r] = fmaf(zv[r].z, wa[2], acc0[r]);
            acc0[r] = fmaf(zv[r].w, wa[3], acc0[r]);
            acc1[r] = fmaf(zv[r].x, wb[0], acc1[r]);
            acc1[r] = fmaf(zv[r].y, wb[1], acc1[r]);
            acc1[r] = fmaf(zv[r].z, wb[2], acc1[r]);
            acc1[r] = fmaf(zv[r].w, wb[3], acc1[r]);
        }
    }
    float* ub = u + (size_t)row0 * HIDDEN;
    #pragma unroll
    for (int r = 0; r < 8; ++r) {
        ub[r * HIDDEN + lane]      = acc0[r];
        ub[r * HIDDEN + lane + 64] = acc1[r];
    }
}

// out[e] = sigmoid(dot(U[src[e]], z[dst[e]])), 16 lanes per edge.
__global__ __launch_bounds__(256) void edge_score(const float* __restrict__ u,
                                                  const float* __restrict__ z,
                                                  const int* __restrict__ eidx,
                                                  float* __restrict__ out, int E) {
    int tid = threadIdx.x;
    int g = tid >> 4, t = tid & 15;
    int e = blockIdx.x * 16 + g;
    if (e >= E) return;
    int src = eidx[e];
    int dst = eidx[E + e];
    const float4* a = (const float4*)(u + (size_t)src * HIDDEN);
    const float4* b = (const float4*)(z + (size_t)dst * HIDDEN);
    // two fully-coalesced 256 B segments per row
    float4 a0 = a[t],      b0 = b[t];
    float4 a1 = a[t + 16], b1 = b[t + 16];
    float s = a0.x * b0.x + a0.y * b0.y + a0.z * b0.z + a0.w * b0.w
            + a1.x * b1.x + a1.y * b1.y + a1.z * b1.z + a1.w * b1.w;
    #pragma unroll
    for (int off = 8; off > 0; off >>= 1) s += __shfl_down(s, off, 16);
    if (t == 0) out[e] = 1.0f / (1.0f + __expf(-s));
}

extern "C" void kernel_launch(void* const* d_in, const int* in_sizes, int n_in,
                              void* d_out, int out_size, void* d_ws, size_t ws_size,
                              hipStream_t stream) {
    const float* z    = (const float*)d_in[0];
    const int*   eidx = (const int*)d_in[1];
    const float* w    = (const float*)d_in[2];
    float* out = (float*)d_out;

    int nrows = in_sizes[0] / HIDDEN;   // 100000
    int E = out_size;                    // 1000000

    float* wsym = (float*)d_ws;
    float* u    = (float*)d_ws + HIDDEN * HIDDEN;

    symmetrize_w<<<(HIDDEN * HIDDEN) / 256, 256, 0, stream>>>(w, wsym);
    gemm_u<<<(nrows + 31) / 32, 256, 0, stream>>>(z, wsym, u, nrows);
    edge_score<<<(E + 15) / 16, 256, 0, stream>>>(u, z, eidx, out, E);
}

// Round 2
// 184.172 us; speedup vs baseline: 1.7776x; 1.7776x over previous
//
#include <hip/hip_runtime.h>

#define HIDDEN 128
#define LDSW 130   // padded LDS stride (halves) for Wsym^T: word stride 65 -> 2-way alias, free

typedef _Float16 f16;
typedef f16 f16x2 __attribute__((ext_vector_type(2)));
typedef f16 f16x4 __attribute__((ext_vector_type(4)));

static __device__ __forceinline__ float fdot2(f16x2 a, f16x2 b, float c) {
    // v_dot2_f32_f16: fp16 pair dot, fp32 accumulate (gfx9+/CDNA)
    return __builtin_amdgcn_fdot2(a, b, c, false);
}

// wsh_t[j][k] = Wsym[k][j] = w[k][j] + w[j][k]  (col-major Wsym, fp16)
__global__ __launch_bounds__(256) void prep_w(const float* __restrict__ w,
                                              f16* __restrict__ wsh_t) {
    int idx = blockIdx.x * 256 + threadIdx.x;   // 0..16383
    int j = idx >> 7, k = idx & 127;
    wsh_t[idx] = (f16)(w[k * HIDDEN + j] + w[j * HIDDEN + k]);
}

// U = z @ Wsym -> uh (fp16); also emits zh = (fp16)z.
// Block: 256 thr, 32 rows. Wsym^T (fp16, padded) + z-tile (fp16) in LDS = 40.5 KB -> 3 blocks/CU.
// Wave owns 8 rows; lane owns cols {lane, lane+64}. fp32 accumulation via v_dot2_f32_f16.
__global__ __launch_bounds__(256) void gemm_u16(const float* __restrict__ z,
                                               const f16* __restrict__ wsh_t,
                                               f16* __restrict__ zh,
                                               f16* __restrict__ uh) {
    __shared__ f16 wlt[HIDDEN * LDSW];     // 33280 B, [col][k] padded
    __shared__ f16 zt[32 * HIDDEN];        // 8192 B, [row][k]
    int tid = threadIdx.x;

    // Stage Wsym^T: 2048 16B-chunks, coalesced global reads
    {
        const float4* g = (const float4*)wsh_t;
        #pragma unroll
        for (int it = 0; it < 8; ++it) {
            int idx = it * 256 + tid;
            float4 v = g[idx];
            int j = idx >> 4, kc = idx & 15;          // col j, 8-half chunk kc
            f16x2* dst = (f16x2*)&wlt[j * LDSW + kc * 8];
            const f16x2* s = (const f16x2*)&v;
            dst[0] = s[0]; dst[1] = s[1]; dst[2] = s[2]; dst[3] = s[3];
        }
    }
    // Stage z tile (fp32 -> fp16), write LDS + global zh (both coalesced)
    int row0 = blockIdx.x * 32;
    {
        const float4* z4 = (const float4*)(z + (size_t)row0 * HIDDEN);  // 1024 chunks
        f16x2* zl = (f16x2*)zt;
        f16x2* zg = (f16x2*)(zh + (size_t)row0 * HIDDEN);
        #pragma unroll
        for (int it = 0; it < 4; ++it) {
            int idx = it * 256 + tid;
            float4 v = z4[idx];
            f16x2 h0 = {(f16)v.x, (f16)v.y};
            f16x2 h1 = {(f16)v.z, (f16)v.w};
            int r = idx >> 5, c4 = idx & 31;
            zl[r * 64 + c4 * 2]     = h0;
            zl[r * 64 + c4 * 2 + 1] = h1;
            zg[idx * 2]     = h0;
            zg[idx * 2 + 1] = h1;
        }
    }
    __syncthreads();

    int wave = tid >> 6, lane = tid & 63;
    float acc0[8], acc1[8];
    #pragma unroll
    for (int r = 0; r < 8; ++r) { acc0[r] = 0.f; acc1[r] = 0.f; }

    const f16x2* wl2 = (const f16x2*)wlt;   // h2 stride per col = 65
    int c0 = lane * 65, c1 = (lane + 64) * 65;

    #pragma unroll 4
    for (int q = 0; q < 32; ++q) {          // k = 4q .. 4q+3
        f16x2 w00 = wl2[c0 + 2 * q], w01 = wl2[c0 + 2 * q + 1];  // bank: (lane+2q)%32, 2-way free
        f16x2 w10 = wl2[c1 + 2 * q], w11 = wl2[c1 + 2 * q + 1];
        #pragma unroll
        for (int r = 0; r < 8; ++r) {
            f16x4 zv = *(const f16x4*)&zt[(wave * 8 + r) * HIDDEN + 4 * q];  // wave-uniform broadcast
            f16x2 z0 = {zv.x, zv.y}, z1 = {zv.z, zv.w};
            acc0[r] = fdot2(z1, w01, fdot2(z0, w00, acc0[r]));
            acc1[r] = fdot2(z1, w11, fdot2(z0, w10, acc1[r]));
        }
    }

    f16* ub = uh + (size_t)(row0 + wave * 8) * HIDDEN;
    #pragma unroll
    for (int r = 0; r < 8; ++r) {
        ub[r * HIDDEN + lane]      = (f16)acc0[r];
        ub[r * HIDDEN + lane + 64] = (f16)acc1[r];
    }
}

// out[e] = sigmoid(dot(uh[src[e]], zh[dst[e]])) — 16 lanes/edge, one dwordx4 per side.
__global__ __launch_bounds__(256) void edge_score16(const f16* __restrict__ uh,
                                                    const f16* __restrict__ zh,
                                                    const int* __restrict__ eidx,
                                                    float* __restrict__ out, int E) {
    int tid = threadIdx.x;
    int g = tid >> 4, t = tid & 15;
    int e = blockIdx.x * 16 + g;
    if (e >= E) return;
    int src = eidx[e];
    int dst = eidx[E + e];
    const float4* a4 = (const float4*)(uh + (size_t)src * HIDDEN);
    const float4* b4 = (const float4*)(zh + (size_t)dst * HIDDEN);
    float4 av = a4[t], bv = b4[t];        // 16 lanes x 16 B = full 256 B row, coalesced
    const f16x2* ap = (const f16x2*)&av;
    const f16x2* bp = (const f16x2*)&bv;
    float s = 0.f;
    #pragma unroll
    for (int i = 0; i < 4; ++i) s = fdot2(ap[i], bp[i], s);
    #pragma unroll
    for (int off = 8; off > 0; off >>= 1) s += __shfl_down(s, off, 16);
    if (t == 0) out[e] = 1.0f / (1.0f + __expf(-s));
}

extern "C" void kernel_launch(void* const* d_in, const int* in_sizes, int n_in,
                              void* d_out, int out_size, void* d_ws, size_t ws_size,
                              hipStream_t stream) {
    const float* z    = (const float*)d_in[0];
    const int*   eidx = (const int*)d_in[1];
    const float* w    = (const float*)d_in[2];
    float* out = (float*)d_out;

    int nrows = in_sizes[0] / HIDDEN;   // 100000 (multiple of 32)
    int E = out_size;                    // 1000000

    f16* wsh_t = (f16*)d_ws;                         // 16384 halves (32 KB)
    f16* zh    = wsh_t + HIDDEN * HIDDEN;            // 12.8M halves (25.6 MB)
    f16* uh    = zh + (size_t)nrows * HIDDEN;        // 12.8M halves (25.6 MB)

    prep_w<<<(HIDDEN * HIDDEN) / 256, 256, 0, stream>>>(w, wsh_t);
    gemm_u16<<<nrows / 32, 256, 0, stream>>>(z, wsh_t, zh, uh);
    edge_score16<<<(E + 15) / 16, 256, 0, stream>>>(uh, zh, eidx, out, E);
}